// Round 5
// baseline (195.379 us; speedup 1.0000x reference)
//
#include <hip/hip_runtime.h>
#include <cstdint>

// Problem constants (fixed by reference)
#define NB      8
#define NN      4096
#define NCLS    80
#define MAXDET  300

// Output float layout (flat, 16808 elements)
#define OFF_IDX  0
#define OFF_SCR  2400
#define OFF_BOX  4800
#define OFF_CLS  14400
#define OFF_NDT  16800

// IoU > thr test, matching reference arithmetic exactly (no FMA contraction).
__device__ __forceinline__ bool iou_gt(float c0, float c1, float c2, float c3,
                                       float t0, float t1, float t2, float t3,
                                       float tarea)
{
#pragma clang fp contract(off)
    float xx1 = fmaxf(c0, t0);
    float yy1 = fmaxf(c1, t1);
    float xx2 = fminf(c2, t2);
    float yy2 = fminf(c3, t3);
    float w = xx2 - xx1; w = fmaxf(w, 0.0f);
    float h = yy2 - yy1; h = fmaxf(h, 0.0f);
    float inter = w * h;
    float areac = (c2 - c0) * (c3 - c1);
    float uni = areac + tarea - inter;
    return (inter / uni) > 0.65f;
}

__device__ __forceinline__ uint64_t shfl_xor64(uint64_t x, int m)
{
    unsigned lo = __shfl_xor((unsigned)x, m, 64);
    unsigned hi = __shfl_xor((unsigned)(x >> 32), m, 64);
    return ((uint64_t)hi << 32) | lo;
}

__device__ __forceinline__ void ce64(uint64_t& a, uint64_t& b, bool desc)
{
    uint64_t lo = (a < b) ? a : b;
    uint64_t hi = (a < b) ? b : a;
    a = desc ? hi : lo;
    b = desc ? lo : hi;
}

// =================== one block per batch; zero inter-block traffic ===================
// 8 blocks x 1024 threads (16 waves). Per block:
//   scan:   stage scores (f32) + validity-encoded class bytes into LDS.
//   NMS:    wave wv handles classes {wv, wv+16, ..., wv+64}. Per class: ballot-based
//           compaction from LDS class bytes -> in-wave bitonic sort (64 or 128) ->
//           IoU matrix + serial-ballot greedy suppress (wave-local LDS scratch) ->
//           survivors recorded in a 4096-bit element bitmask + fused score histogram.
//   select: exact-bin cutoff -> gather <=512 candidates -> wave-0 in-register
//           bitonic-512 (fully unrolled, VGPR-resident) -> pack outputs.
// No workspace, no fences, no global atomics, no memset.
__global__ __launch_bounds__(1024)
void k_nms_batch(const float* __restrict__ scores,
                 const float* __restrict__ boxes,
                 const int*   __restrict__ classes,
                 float* __restrict__ out)
{
    const int b    = blockIdx.x;
    const int tid  = threadIdx.x;
    const int lane = tid & 63;
    const int wv   = tid >> 6;
    const int bN   = b * NN;
    const uint64_t lmask = (1ull << lane) - 1ull;

    __shared__ alignas(16) float         score_s[NN];        // 16 KB
    __shared__ alignas(16) unsigned char cls8[NN];           //  4 KB (0xFF = invalid)
    __shared__ alignas(16) uint64_t      wscr[16 * 160];     // 20 KB: per-wave scratch (keys / boxes+areas)
    __shared__ int      hist[256];                           //  1 KB
    __shared__ uint64_t cand[512];                           //  4 KB
    __shared__ unsigned aliveE[NN / 32];                     //  0.5 KB survivor bitmask
    __shared__ int      keptn_s, ncand_s, cutoff_s;

    // ---- init + static output fills (out poisoned each replay) ----
    if (tid < NN / 32) aliveE[tid] = 0u;
    if (tid < 256) hist[tid] = 0;
    if (tid == 0) { keptn_s = 0; ncand_s = 0; cutoff_s = 256; }
    if (tid < MAXDET) {
        out[OFF_IDX + b * MAXDET + tid] = -1.0f;
        out[OFF_SCR + b * MAXDET + tid] = 0.0f;
        int ob = OFF_BOX + (b * MAXDET + tid) * 4;
        out[ob + 0] = 0.0f; out[ob + 1] = 0.0f;
        out[ob + 2] = 0.0f; out[ob + 3] = 0.0f;
        out[OFF_CLS + b * MAXDET + tid] = 0.0f;
    }

    // ---- scan: thread t stages elements 4t..4t+3 ----
    {
        const float4 sv = ((const float4*)(scores + bN))[tid];
        const int4   cv = ((const int4*)(classes + bN))[tid];
        ((float4*)score_s)[tid] = sv;
        unsigned p0 = (sv.x > 0.05f) ? (unsigned)cv.x : 0xFFu;
        unsigned p1 = (sv.y > 0.05f) ? (unsigned)cv.y : 0xFFu;
        unsigned p2 = (sv.z > 0.05f) ? (unsigned)cv.z : 0xFFu;
        unsigned p3 = (sv.w > 0.05f) ? (unsigned)cv.w : 0xFFu;
        ((unsigned*)cls8)[tid] = p0 | (p1 << 8) | (p2 << 16) | (p3 << 24);
    }
    __syncthreads();

    // ---- per-class NMS: wave wv owns classes wv + 16q ----
    uint64_t* wk  = &wscr[wv * 160];          // [0..127] compact keys (u64)
    float4*   wbx = (float4*)wk;              // overlay: staged boxes (fast path)
    float*    war = (float*)(wk + 128);       // staged areas
    const float4*   boxes4 = (const float4*)boxes;
    const unsigned* clsu   = (const unsigned*)cls8;

    for (int q = 0; q < 5; ++q) {
        const unsigned c = (unsigned)(wv + (q << 4));

        // ballot compaction: 16 iters x 256 elements (4 bytes/lane)
        int cnt = 0;
        for (int it = 0; it < 16; ++it) {
            const unsigned d = clsu[(it << 6) | lane];
            const bool m0 = ((d      ) & 0xFFu) == c;
            const bool m1 = ((d >>  8) & 0xFFu) == c;
            const bool m2 = ((d >> 16) & 0xFFu) == c;
            const bool m3 = ( d >> 24        ) == c;
            const uint64_t B0 = __ballot(m0), B1 = __ballot(m1);
            const uint64_t B2 = __ballot(m2), B3 = __ballot(m3);
            int r = cnt + __popcll(B0 & lmask) + __popcll(B1 & lmask)
                        + __popcll(B2 & lmask) + __popcll(B3 & lmask);
            const int e0 = ((it << 6) | lane) << 2;
            if (m0) { if (r < 128) wk[r] = (((uint64_t)(__float_as_uint(score_s[e0 + 0]) | 0x80000000u)) << 32) | (unsigned)(e0 + 0); ++r; }
            if (m1) { if (r < 128) wk[r] = (((uint64_t)(__float_as_uint(score_s[e0 + 1]) | 0x80000000u)) << 32) | (unsigned)(e0 + 1); ++r; }
            if (m2) { if (r < 128) wk[r] = (((uint64_t)(__float_as_uint(score_s[e0 + 2]) | 0x80000000u)) << 32) | (unsigned)(e0 + 2); ++r; }
            if (m3) { if (r < 128) wk[r] = (((uint64_t)(__float_as_uint(score_s[e0 + 3]) | 0x80000000u)) << 32) | (unsigned)(e0 + 3); ++r; }
            cnt += __popcll(B0) + __popcll(B1) + __popcll(B2) + __popcll(B3);
        }
        const int nc = cnt > 128 ? 128 : cnt;
        if (nc <= 0) continue;

        if (nc <= 64) {
            // ---- fast path: in-wave descending bitonic of 64 keys ----
            uint64_t key = (lane < nc) ? wk[lane] : 0ull;
            for (int k = 2; k <= 64; k <<= 1) {
                bool up = ((lane & k) == 0);
                for (int j = k >> 1; j >= 1; j >>= 1) {
                    uint64_t w = shfl_xor64(key, j);
                    bool km = (((lane & j) == 0) == up);
                    key = km ? (key > w ? key : w) : (key < w ? key : w);
                }
            }
            const unsigned idx = (unsigned)key;
            float4 bx = make_float4(0, 0, 0, 0);
            float  area = 0.0f;
            if (lane < nc) {
                bx = boxes4[bN + idx];
                {
#pragma clang fp contract(off)
                    area = (bx.z - bx.x) * (bx.w - bx.y);
                }
            }
            wbx[lane] = bx;              // keys already in regs; scratch reuse OK
            war[lane] = area;
            uint64_t ov = 0;
            for (int j0 = 0; j0 < nc - 1; j0 += 4) {
                float4 t[4]; float ta[4];
#pragma unroll
                for (int r = 0; r < 4; ++r) { t[r] = wbx[j0 + r]; ta[r] = war[j0 + r]; }
#pragma unroll
                for (int r = 0; r < 4; ++r) {
                    int j = j0 + r;
                    if (j < nc - 1 && lane > j && lane < nc &&
                        iou_gt(bx.x, bx.y, bx.z, bx.w,
                               t[r].x, t[r].y, t[r].z, t[r].w, ta[r]))
                        ov |= 1ull << j;
                }
            }
            uint64_t alive = (nc >= 64) ? ~0ull : ((1ull << nc) - 1ull);
            for (int t = 0; t < nc; ++t) {
                if (!((alive >> t) & 1ull)) continue;
                uint64_t die = __ballot(((ov >> t) & 1ull) != 0);
                alive &= ~die;
            }
            if (lane == 0) atomicAdd(&keptn_s, __popcll(alive));
            if (lane < nc && ((alive >> lane) & 1ull)) {
                unsigned e = (unsigned)key;
                atomicOr(&aliveE[e >> 5], 1u << (e & 31));
                float f = __uint_as_float((unsigned)(key >> 32) & 0x7FFFFFFFu);
                int bin = (int)(f * 256.0f); bin = bin > 255 ? 255 : bin;
                atomicAdd(&hist[bin], 1);
            }
        } else {
            // ---- medium path (rare, nc in 65..128): 2-reg bitonic + shfl IoU ----
            const int mB = 64 + lane;
            uint64_t kA = (lane < nc) ? wk[lane] : 0ull;
            uint64_t kB = (mB < nc) ? wk[mB] : 0ull;
            for (int k = 2; k <= 128; k <<= 1) {
                bool up0 = ((lane & k) == 0);
                bool up1 = ((mB & k) == 0);
                for (int j = k >> 1; j >= 1; j >>= 1) {
                    if (j == 64) {
                        ce64(kA, kB, up0);   // k==128 here: up0 == true
                    } else {
                        uint64_t wA = shfl_xor64(kA, j);
                        uint64_t wB = shfl_xor64(kB, j);
                        bool kmA = (((lane & j) == 0) == up0);
                        bool kmB = (((lane & j) == 0) == up1);
                        kA = kmA ? (kA > wA ? kA : wA) : (kA < wA ? kA : wA);
                        kB = kmB ? (kB > wB ? kB : wB) : (kB < wB ? kB : wB);
                    }
                }
            }
            const unsigned idxA = (unsigned)kA, idxB = (unsigned)kB;
            float4 bA = make_float4(0, 0, 0, 0), bB = bA;
            float  aA = 0.0f, aB = 0.0f;
            if (lane < nc) {
                bA = boxes4[bN + idxA];
                {
#pragma clang fp contract(off)
                    aA = (bA.z - bA.x) * (bA.w - bA.y);
                }
            }
            if (mB < nc) {
                bB = boxes4[bN + idxB];
                {
#pragma clang fp contract(off)
                    aB = (bB.z - bB.x) * (bB.w - bB.y);
                }
            }
            uint64_t ovA0 = 0, ovB0 = 0, ovB1 = 0;
            for (int j = 0; j < nc - 1; ++j) {
                float t0, t1, t2, t3, ta;
                if (j < 64) {
                    t0 = __shfl(bA.x, j, 64); t1 = __shfl(bA.y, j, 64);
                    t2 = __shfl(bA.z, j, 64); t3 = __shfl(bA.w, j, 64);
                    ta = __shfl(aA, j, 64);
                    if (lane > j && lane < nc &&
                        iou_gt(bA.x, bA.y, bA.z, bA.w, t0, t1, t2, t3, ta))
                        ovA0 |= 1ull << j;
                    if (mB < nc &&
                        iou_gt(bB.x, bB.y, bB.z, bB.w, t0, t1, t2, t3, ta))
                        ovB0 |= 1ull << j;
                } else {
                    int js = j - 64;
                    t0 = __shfl(bB.x, js, 64); t1 = __shfl(bB.y, js, 64);
                    t2 = __shfl(bB.z, js, 64); t3 = __shfl(bB.w, js, 64);
                    ta = __shfl(aB, js, 64);
                    if (mB > j && mB < nc &&
                        iou_gt(bB.x, bB.y, bB.z, bB.w, t0, t1, t2, t3, ta))
                        ovB1 |= 1ull << js;
                }
            }
            uint64_t alive0 = (nc >= 64) ? ~0ull : ((1ull << nc) - 1ull);
            uint64_t alive1 = (nc >= 128) ? ~0ull : ((1ull << (nc - 64)) - 1ull);
            for (int t = 0; t < nc; ++t) {
                if (t < 64) {
                    if (!((alive0 >> t) & 1ull)) continue;
                    uint64_t d0 = __ballot(((ovA0 >> t) & 1ull) != 0);
                    uint64_t d1 = __ballot(((ovB0 >> t) & 1ull) != 0);
                    alive0 &= ~d0;
                    alive1 &= ~d1;
                } else {
                    int tt = t - 64;
                    if (!((alive1 >> tt) & 1ull)) continue;
                    uint64_t d1 = __ballot(((ovB1 >> tt) & 1ull) != 0);
                    alive1 &= ~d1;
                }
            }
            if (lane == 0) atomicAdd(&keptn_s, __popcll(alive0) + __popcll(alive1));
            if (lane < nc && ((alive0 >> lane) & 1ull)) {
                unsigned e = (unsigned)kA;
                atomicOr(&aliveE[e >> 5], 1u << (e & 31));
                float f = __uint_as_float((unsigned)(kA >> 32) & 0x7FFFFFFFu);
                int bin = (int)(f * 256.0f); bin = bin > 255 ? 255 : bin;
                atomicAdd(&hist[bin], 1);
            }
            if (mB < nc && ((alive1 >> lane) & 1ull)) {
                unsigned e = (unsigned)kB;
                atomicOr(&aliveE[e >> 5], 1u << (e & 31));
                float f = __uint_as_float((unsigned)(kB >> 32) & 0x7FFFFFFFu);
                int bin = (int)(f * 256.0f); bin = bin > 255 ? 255 : bin;
                atomicAdd(&hist[bin], 1);
            }
        }
    }
    __syncthreads();

    // ---- cutoff: exact 1-bin granularity (wave 0) ----
    const int kept_n = keptn_s;
    const int target = kept_n < MAXDET ? kept_n : MAXDET;
    if (tid == 0) out[OFF_NDT + b] = (float)target;
    if (wv == 0) {
        int h0 = hist[4 * lane + 0], h1 = hist[4 * lane + 1];
        int h2 = hist[4 * lane + 2], h3 = hist[4 * lane + 3];
        int s = h0 + h1 + h2 + h3;
#pragma unroll
        for (int off = 1; off < 64; off <<= 1) {
            int t = __shfl_down(s, off, 64);
            if (lane + off < 64) s += t;
        }
        int snext = __shfl_down(s, 1, 64);
        if (lane == 63) snext = 0;
        int u0 = s;            // suffix(4L)
        int u1 = u0 - h0;      // suffix(4L+1)
        int u2 = u1 - h1;      // suffix(4L+2)
        int u3 = u2 - h2;      // suffix(4L+3)
        int u4 = snext;        // suffix(4L+4)
        if (target > 0) {
            if (u0 >= target && u1 < target) cutoff_s = 4 * lane + 0;
            if (u1 >= target && u2 < target) cutoff_s = 4 * lane + 1;
            if (u2 >= target && u3 < target) cutoff_s = 4 * lane + 2;
            if (u3 >= target && u4 < target) cutoff_s = 4 * lane + 3;
        }
    }
    __syncthreads();
    const int cutoff = cutoff_s;

    // ---- gather candidates from survivor bitmask (all 1024 threads) ----
#pragma unroll
    for (int k2 = 0; k2 < 4; ++k2) {
        const int e = (tid << 2) | k2;
        if ((aliveE[e >> 5] >> (e & 31)) & 1u) {
            float f = score_s[e];
            int bin = (int)(f * 256.0f); bin = bin > 255 ? 255 : bin;
            if (bin >= cutoff) {
                int slot = atomicAdd(&ncand_s, 1);
                if (slot < 512)
                    cand[slot] = (((uint64_t)(__float_as_uint(f) | 0x80000000u)) << 32) | (unsigned)e;
            }
        }
    }
    __syncthreads();
    const int ncand = ncand_s < 512 ? ncand_s : 512;
    if (tid < 512 && tid >= ncand) cand[tid] = 0ull;
    __syncthreads();

    if (wv != 0) return;   // only wave 0 sorts + packs

    // ---- descending bitonic sort of 512 u64 keys in one wave (8 regs/lane) ----
    // element index i = (e<<6) | lane. FULLY UNROLLED so v[] stays in VGPRs.
    uint64_t v[8];
#pragma unroll
    for (int e = 0; e < 8; ++e) v[e] = cand[(e << 6) | lane];
#pragma unroll
    for (int kk = 1; kk <= 9; ++kk) {
        const int k = 1 << kk;
#pragma unroll
        for (int jj = kk - 1; jj >= 0; --jj) {
            const int j = 1 << jj;
            if (j >= 64) {
                const int m = j >> 6;        // 1, 2 or 4 (literal after unroll)
#pragma unroll
                for (int e = 0; e < 8; ++e) {
                    if ((e & m) == 0) {
                        const bool desc = (((e << 6) & k) == 0);
                        ce64(v[e], v[e | m], desc);
                    }
                }
            } else {
#pragma unroll
                for (int e = 0; e < 8; ++e) {
                    const int ebit = (e << 6) & k;        // static per e
                    bool up = (k < 64) ? ((lane & k) == 0) : (ebit == 0);
                    uint64_t w = shfl_xor64(v[e], j);
                    bool km = (((lane & j) == 0) == up);
                    v[e] = km ? (v[e] > w ? v[e] : w) : (v[e] < w ? v[e] : w);
                }
            }
        }
    }

    // ---- pack top-target detections (rank = sorted position) ----
#pragma unroll
    for (int e = 0; e < 8; ++e) {
        const int rank = (e << 6) | lane;
        if (rank < target) {
            const uint64_t kv = v[e];
            const unsigned idx = (unsigned)kv;
            out[OFF_SCR + b * MAXDET + rank] = __uint_as_float((unsigned)(kv >> 32) & 0x7FFFFFFFu);
            float4 g = boxes4[bN + idx];
            int ob = OFF_BOX + (b * MAXDET + rank) * 4;
            out[ob + 0] = g.x; out[ob + 1] = g.y;
            out[ob + 2] = g.z; out[ob + 3] = g.w;
            out[OFF_CLS + b * MAXDET + rank] = (float)cls8[idx];
        }
    }
}

extern "C" void kernel_launch(void* const* d_in, const int* in_sizes, int n_in,
                              void* d_out, int out_size, void* d_ws, size_t ws_size,
                              hipStream_t stream)
{
    const float* scores  = (const float*)d_in[0];
    const float* boxes   = (const float*)d_in[1];
    const int*   classes = (const int*)d_in[2];
    float*       out     = (float*)d_out;

    hipLaunchKernelGGL(k_nms_batch, dim3(NB), dim3(1024), 0, stream,
                       scores, boxes, classes, out);
}